// Round 1
// baseline (121.639 us; speedup 1.0000x reference)
//
#include <hip/hip_runtime.h>

#ifndef __has_builtin
#define __has_builtin(x) 0
#endif

#if __has_builtin(__builtin_amdgcn_exp2f)
#define EXP2F(x) __builtin_amdgcn_exp2f(x)
#else
#define EXP2F(x) exp2f(x)
#endif
#if __has_builtin(__builtin_amdgcn_rcpf)
#define RCPF(x) __builtin_amdgcn_rcpf(x)
#else
#define RCPF(x) (1.0f / (x))
#endif

static constexpr int NB = 4, NQ = 512, NK = 512, DD = 512, HH = 128, DV = 512;
static constexpr float MASKV = -1e6f;
static constexpr float C2LOG2E = 2.885390081777926814f;  // 2*log2(e)

// ---------------------------------------------------------------------------
// K1: out[b][r][h] = sum_d in[b][r][d] * W[d][h]   (f32, H=128)
// grid = NB*128 blocks (4 rows each), 256 threads = 128 h x 2 row-groups
// use_mask=1 (keys): skip blocks whose rows are all >= valid_len (never read).
// ---------------------------------------------------------------------------
__global__ __launch_bounds__(256) void proj_kernel(
    const float* __restrict__ in, const float* __restrict__ W,
    float* __restrict__ out, const int* __restrict__ valid_lens, int use_mask) {
  const int b = blockIdx.x >> 7;
  const int r0 = (blockIdx.x & 127) << 2;
  if (use_mask) {
    const int vl = valid_lens[b];
    if (r0 >= vl) return;  // rows never consumed downstream
  }
  const int h = threadIdx.x & 127;
  const int rg = threadIdx.x >> 7;  // 0,1
  const float* in0 = in + ((size_t)(b * NQ + r0 + rg)) * DD;
  const float* in1 = in0 + 2 * DD;
  float acc0 = 0.f, acc1 = 0.f;
  for (int d = 0; d < DD; d += 4) {
    const float4 x0 = *reinterpret_cast<const float4*>(in0 + d);
    const float4 x1 = *reinterpret_cast<const float4*>(in1 + d);
    const float w0 = W[(d + 0) * HH + h];
    const float w1 = W[(d + 1) * HH + h];
    const float w2 = W[(d + 2) * HH + h];
    const float w3 = W[(d + 3) * HH + h];
    acc0 = fmaf(x0.x, w0, acc0); acc0 = fmaf(x0.y, w1, acc0);
    acc0 = fmaf(x0.z, w2, acc0); acc0 = fmaf(x0.w, w3, acc0);
    acc1 = fmaf(x1.x, w0, acc1); acc1 = fmaf(x1.y, w1, acc1);
    acc1 = fmaf(x1.z, w2, acc1); acc1 = fmaf(x1.w, w3, acc1);
  }
  out[((size_t)(b * NQ + r0 + rg)) * HH + h] = acc0;
  out[((size_t)(b * NQ + r0 + rg + 2)) * HH + h] = acc1;
}

// ---------------------------------------------------------------------------
// K2: scores + masked softmax, fused. One block = (batch b, 8 q-rows).
// 512 threads: thread t owns key k=t for the scores phase; wave w owns
// q-row w for the softmax phase. Writes attnT[b][k][q] (k-major).
// ---------------------------------------------------------------------------
__global__ __launch_bounds__(512) void scores_softmax_kernel(
    const float* __restrict__ qp, const float* __restrict__ kp,
    const float* __restrict__ Wv, const int* __restrict__ valid_lens,
    float* __restrict__ attnT) {
  const int b = blockIdx.x >> 6;
  const int q0 = (blockIdx.x & 63) << 3;
  const int t = threadIdx.x;

  __shared__ __align__(16) float qs[8][HH];  // qp rows, pre-scaled by 2*log2e
  __shared__ __align__(16) float wv[HH];
  __shared__ float sc[8][NK];

  for (int i = t; i < 8 * HH; i += 512) {
    const int q = i >> 7, hh = i & 127;
    qs[q][hh] = qp[((size_t)(b * NQ + q0 + q)) * HH + hh] * C2LOG2E;
  }
  if (t < HH) wv[t] = Wv[t];
  __syncthreads();

  const int vl = valid_lens[b];
  float s[8];
#pragma unroll
  for (int q = 0; q < 8; ++q) s[q] = MASKV;

  if (t < vl) {  // masked keys: skip all tanh work (avg ~2x saving)
#pragma unroll
    for (int q = 0; q < 8; ++q) s[q] = 0.f;
    const float* kprow = kp + ((size_t)(b * NK + t)) * HH;
    for (int hs = 0; hs < HH; hs += 4) {
      const float4 k4 = *reinterpret_cast<const float4*>(kprow + hs);
      const float4 w4 = *reinterpret_cast<const float4*>(&wv[hs]);
      const float kx0 = k4.x * C2LOG2E;
      const float kx1 = k4.y * C2LOG2E;
      const float kx2 = k4.z * C2LOG2E;
      const float kx3 = k4.w * C2LOG2E;
#pragma unroll
      for (int q = 0; q < 8; ++q) {
        const float4 q4 = *reinterpret_cast<const float4*>(&qs[q][hs]);
        float e, r, th;
        // tanh(x) = 1 - 2/(exp2(2x*log2e)+1); args pre-scaled by 2*log2e
        e = EXP2F(kx0 + q4.x); r = RCPF(e + 1.f); th = fmaf(-2.f, r, 1.f); s[q] = fmaf(w4.x, th, s[q]);
        e = EXP2F(kx1 + q4.y); r = RCPF(e + 1.f); th = fmaf(-2.f, r, 1.f); s[q] = fmaf(w4.y, th, s[q]);
        e = EXP2F(kx2 + q4.z); r = RCPF(e + 1.f); th = fmaf(-2.f, r, 1.f); s[q] = fmaf(w4.z, th, s[q]);
        e = EXP2F(kx3 + q4.w); r = RCPF(e + 1.f); th = fmaf(-2.f, r, 1.f); s[q] = fmaf(w4.w, th, s[q]);
      }
    }
  }
#pragma unroll
  for (int q = 0; q < 8; ++q) sc[q][t] = s[q];
  __syncthreads();

  // softmax: wave w handles q-row w (8 waves, 8 rows)
  const int w = t >> 6, l = t & 63;
  float v[8];
#pragma unroll
  for (int j = 0; j < 8; ++j) v[j] = sc[w][l + (j << 6)];
  float m = v[0];
#pragma unroll
  for (int j = 1; j < 8; ++j) m = fmaxf(m, v[j]);
#pragma unroll
  for (int off = 32; off > 0; off >>= 1) m = fmaxf(m, __shfl_xor(m, off, 64));
  float p[8], sum = 0.f;
#pragma unroll
  for (int j = 0; j < 8; ++j) {
    p[j] = __expf(v[j] - m);  // masked: exp(-1e6 - m) underflows to exactly 0
    sum += p[j];
  }
#pragma unroll
  for (int off = 32; off > 0; off >>= 1) sum += __shfl_xor(sum, off, 64);
  const float inv = RCPF(sum);
#pragma unroll
  for (int j = 0; j < 8; ++j) sc[w][l + (j << 6)] = p[j] * inv;
  __syncthreads();

  // repack: thread t writes attnT[b][k=t][q0..q0+7] as two float4 (32B/lane)
  const float4 o0 = make_float4(sc[0][t], sc[1][t], sc[2][t], sc[3][t]);
  const float4 o1 = make_float4(sc[4][t], sc[5][t], sc[6][t], sc[7][t]);
  float* dst = attnT + ((size_t)(b * NK + t)) * NQ + q0;
  *reinterpret_cast<float4*>(dst) = o0;
  *reinterpret_cast<float4*>(dst + 4) = o1;
}

// ---------------------------------------------------------------------------
// K3: partial[ks][b][q][v] = sum_{k in ks-range} attnT[b][k][q]*values[b][k][v]
// 128x128 C-tile, 8x8 micro-tile (two 4-wide subtiles), BK=16, 4-way K-split
// -> 256 blocks (full chip). Both LDS tiles staged linearly (k-major inputs).
// ---------------------------------------------------------------------------
__global__ __launch_bounds__(256) void pv_gemm_kernel(
    const float* __restrict__ attnT, const float* __restrict__ values,
    float* __restrict__ partial) {
  const int bid = blockIdx.x;
  const int ks = bid & 3;
  const int tile = (bid >> 2) & 15;
  const int b = bid >> 6;
  const int q0 = (tile >> 2) << 7;
  const int v0 = (tile & 3) << 7;
  const int kbase = ks << 7;

  __shared__ __align__(16) float aT[16][128];
  __shared__ __align__(16) float bS[16][128];

  const int tid = threadIdx.x;
  const int tv = tid & 15, tq = tid >> 4;

  float acc[8][8];
#pragma unroll
  for (int i = 0; i < 8; ++i)
#pragma unroll
    for (int j = 0; j < 8; ++j) acc[i][j] = 0.f;

  for (int kt = 0; kt < 8; ++kt) {
    const int k0 = kbase + (kt << 4);
#pragma unroll
    for (int f = 0; f < 2; ++f) {
      const int id = tid + (f << 8);
      const int dk = id >> 5, c4 = (id & 31) << 2;
      *reinterpret_cast<float4*>(&aT[dk][c4]) =
          *reinterpret_cast<const float4*>(attnT + ((size_t)(b * NK + k0 + dk)) * NQ + q0 + c4);
      *reinterpret_cast<float4*>(&bS[dk][c4]) =
          *reinterpret_cast<const float4*>(values + ((size_t)(b * NK + k0 + dk)) * DV + v0 + c4);
    }
    __syncthreads();
#pragma unroll
    for (int dk = 0; dk < 16; ++dk) {
      const float4 a0 = *reinterpret_cast<const float4*>(&aT[dk][tq << 2]);
      const float4 a1 = *reinterpret_cast<const float4*>(&aT[dk][64 + (tq << 2)]);
      const float4 b0 = *reinterpret_cast<const float4*>(&bS[dk][tv << 2]);
      const float4 b1 = *reinterpret_cast<const float4*>(&bS[dk][64 + (tv << 2)]);
      const float av[8] = {a0.x, a0.y, a0.z, a0.w, a1.x, a1.y, a1.z, a1.w};
      const float bv[8] = {b0.x, b0.y, b0.z, b0.w, b1.x, b1.y, b1.z, b1.w};
#pragma unroll
      for (int i = 0; i < 8; ++i)
#pragma unroll
        for (int j = 0; j < 8; ++j) acc[i][j] = fmaf(av[i], bv[j], acc[i][j]);
    }
    __syncthreads();
  }

  float* pbase = partial + ((size_t)(ks * NB + b)) * NQ * DV;
#pragma unroll
  for (int i = 0; i < 8; ++i) {
    const int q = (i < 4) ? ((tq << 2) + i) : (64 + (tq << 2) + (i - 4));
    const float4 s0 = make_float4(acc[i][0], acc[i][1], acc[i][2], acc[i][3]);
    const float4 s1 = make_float4(acc[i][4], acc[i][5], acc[i][6], acc[i][7]);
    float* row = pbase + ((size_t)(q0 + q)) * DV + v0;
    *reinterpret_cast<float4*>(row + (tv << 2)) = s0;
    *reinterpret_cast<float4*>(row + 64 + (tv << 2)) = s1;
  }
}

// ---------------------------------------------------------------------------
// K4: out = sum of the 4 K-split partials (deterministic, no atomics)
// ---------------------------------------------------------------------------
__global__ __launch_bounds__(256) void reduce4_kernel(
    const float* __restrict__ partial, float* __restrict__ out) {
  const int i = blockIdx.x * 256 + threadIdx.x;  // float4 index, 262144 total
  const float4* p = reinterpret_cast<const float4*>(partial);
  const float4 a = p[i];
  const float4 b = p[i + 262144];
  const float4 c = p[i + 524288];
  const float4 d = p[i + 786432];
  float4 r;
  r.x = a.x + b.x + c.x + d.x;
  r.y = a.y + b.y + c.y + d.y;
  r.z = a.z + b.z + c.z + d.z;
  r.w = a.w + b.w + c.w + d.w;
  reinterpret_cast<float4*>(out)[i] = r;
}

extern "C" void kernel_launch(void* const* d_in, const int* in_sizes, int n_in,
                              void* d_out, int out_size, void* d_ws, size_t ws_size,
                              hipStream_t stream) {
  (void)in_sizes; (void)n_in; (void)out_size; (void)ws_size;
  const float* queries = (const float*)d_in[0];
  const float* keys    = (const float*)d_in[1];
  const float* values  = (const float*)d_in[2];
  const float* Wq      = (const float*)d_in[3];
  const float* Wk      = (const float*)d_in[4];
  const float* Wv      = (const float*)d_in[5];
  const int*   vlens   = (const int*)d_in[6];
  float* out = (float*)d_out;
  float* ws = (float*)d_ws;

  // ws layout (floats): qp 262144 | kp 262144 | attnT 1048576 | partial 4x1048576
  float* qp    = ws;
  float* kp    = ws + 262144;
  float* attnT = ws + 524288;
  float* part  = ws + 1572864;  // 16 MB

  proj_kernel<<<NB * 128, 256, 0, stream>>>(queries, Wq, qp, vlens, 0);
  proj_kernel<<<NB * 128, 256, 0, stream>>>(keys, Wk, kp, vlens, 1);
  scores_softmax_kernel<<<NB * 64, 512, 0, stream>>>(qp, kp, Wv, vlens, attnT);
  pv_gemm_kernel<<<256, 256, 0, stream>>>(attnT, values, part);
  reduce4_kernel<<<1024, 256, 0, stream>>>(part, out);
}

// Round 2
// 96.910 us; speedup vs baseline: 1.2552x; 1.2552x over previous
//
#include <hip/hip_runtime.h>

#ifndef __has_builtin
#define __has_builtin(x) 0
#endif

#if __has_builtin(__builtin_amdgcn_exp2f)
#define EXP2F(x) __builtin_amdgcn_exp2f(x)
#else
#define EXP2F(x) exp2f(x)
#endif
#if __has_builtin(__builtin_amdgcn_rcpf)
#define RCPF(x) __builtin_amdgcn_rcpf(x)
#else
#define RCPF(x) (1.0f / (x))
#endif

static constexpr int NB = 4, NQ = 512, NK = 512, DD = 512, HH = 128, DV = 512;
static constexpr float MASKV = -1e6f;
static constexpr float C2LOG2E = 2.885390081777926814f;  // 2*log2(e)

// ---------------------------------------------------------------------------
// K1 (merged q+k): out[b][r][h] = exp2( C * sum_d in[b][r][d] * W[d][h] )
// bid<512: queries->eq ; bid>=512: keys->ek (rows >= valid_len skipped,
// they are never read downstream). 4 rows/block, 256 thr = 128h x 2 rowgroups.
// ---------------------------------------------------------------------------
__global__ __launch_bounds__(256) void proj_exp_kernel(
    const float* __restrict__ queries, const float* __restrict__ keys,
    const float* __restrict__ Wq, const float* __restrict__ Wk,
    float* __restrict__ eq, float* __restrict__ ek,
    const int* __restrict__ valid_lens) {
  const int isK = blockIdx.x >> 9;
  const int bid = blockIdx.x & 511;
  const int b = bid >> 7;
  const int r0 = (bid & 127) << 2;
  const float* in;
  const float* W;
  float* out;
  if (isK) {
    if (r0 >= valid_lens[b]) return;
    in = keys; W = Wk; out = ek;
  } else {
    in = queries; W = Wq; out = eq;
  }
  const int h = threadIdx.x & 127;
  const int rg = threadIdx.x >> 7;  // 0,1
  const float* in0 = in + ((size_t)(b * NQ + r0 + rg)) * DD;
  const float* in1 = in0 + 2 * DD;
  float acc0 = 0.f, acc1 = 0.f;
  for (int d = 0; d < DD; d += 4) {
    const float4 x0 = *reinterpret_cast<const float4*>(in0 + d);
    const float4 x1 = *reinterpret_cast<const float4*>(in1 + d);
    const float w0 = W[(d + 0) * HH + h];
    const float w1 = W[(d + 1) * HH + h];
    const float w2 = W[(d + 2) * HH + h];
    const float w3 = W[(d + 3) * HH + h];
    acc0 = fmaf(x0.x, w0, acc0); acc0 = fmaf(x0.y, w1, acc0);
    acc0 = fmaf(x0.z, w2, acc0); acc0 = fmaf(x0.w, w3, acc0);
    acc1 = fmaf(x1.x, w0, acc1); acc1 = fmaf(x1.y, w1, acc1);
    acc1 = fmaf(x1.z, w2, acc1); acc1 = fmaf(x1.w, w3, acc1);
  }
  out[((size_t)(b * NQ + r0 + rg)) * HH + h] = EXP2F(acc0 * C2LOG2E);
  out[((size_t)(b * NQ + r0 + rg + 2)) * HH + h] = EXP2F(acc1 * C2LOG2E);
}

// ---------------------------------------------------------------------------
// K2: scores + masked softmax. One block = (batch b, 4 q-rows); 512 blocks
// laid out so each CU's 2 blocks come from different batches (load balance).
// tanh(q+k) = 1 - 2/(eq*ek + 1): inner loop = fma + rcp + fma (1 trans!).
// score = sum(w) - 2*sum(w*r). Writes attnT[b][k][q] (k-major).
// ---------------------------------------------------------------------------
__global__ __launch_bounds__(512) void scores_softmax_kernel(
    const float* __restrict__ eq, const float* __restrict__ ek,
    const float* __restrict__ Wv, const int* __restrict__ valid_lens,
    float* __restrict__ attnT) {
  const int b = blockIdx.x >> 7;
  const int q0 = (blockIdx.x & 127) << 2;
  const int t = threadIdx.x;

  __shared__ __align__(16) float qs[4][HH];
  __shared__ __align__(16) float wv[HH];
  __shared__ float sc[4][NK];

  qs[t >> 7][t & 127] = eq[((size_t)(b * NQ + q0 + (t >> 7))) * HH + (t & 127)];
  if (t < HH) wv[t] = Wv[t];
  __syncthreads();

  const int vl = valid_lens[b];
  float s[4] = {0.f, 0.f, 0.f, 0.f};
  float sw = 0.f;

  if (t < vl) {
    const float* ekrow = ek + ((size_t)(b * NK + t)) * HH;
    for (int hs = 0; hs < HH; hs += 4) {
      const float4 k4 = *reinterpret_cast<const float4*>(ekrow + hs);
      const float4 w4 = *reinterpret_cast<const float4*>(&wv[hs]);
      sw += (w4.x + w4.y) + (w4.z + w4.w);
#pragma unroll
      for (int q = 0; q < 4; ++q) {
        const float4 q4 = *reinterpret_cast<const float4*>(&qs[q][hs]);
        float d, r;
        d = fmaf(q4.x, k4.x, 1.f); r = RCPF(d); s[q] = fmaf(w4.x, r, s[q]);
        d = fmaf(q4.y, k4.y, 1.f); r = RCPF(d); s[q] = fmaf(w4.y, r, s[q]);
        d = fmaf(q4.z, k4.z, 1.f); r = RCPF(d); s[q] = fmaf(w4.z, r, s[q]);
        d = fmaf(q4.w, k4.w, 1.f); r = RCPF(d); s[q] = fmaf(w4.w, r, s[q]);
      }
    }
  }
#pragma unroll
  for (int q = 0; q < 4; ++q)
    sc[q][t] = (t < vl) ? fmaf(-2.f, s[q], sw) : MASKV;
  __syncthreads();

  // softmax: wave w (<4) handles q-row w over all 512 keys
  const int w = t >> 6, l = t & 63;
  if (w < 4) {
    float v[8];
#pragma unroll
    for (int j = 0; j < 8; ++j) v[j] = sc[w][l + (j << 6)];
    float m = v[0];
#pragma unroll
    for (int j = 1; j < 8; ++j) m = fmaxf(m, v[j]);
#pragma unroll
    for (int off = 32; off > 0; off >>= 1) m = fmaxf(m, __shfl_xor(m, off, 64));
    float p[8], sum = 0.f;
#pragma unroll
    for (int j = 0; j < 8; ++j) {
      p[j] = __expf(v[j] - m);  // masked: underflows to exactly 0
      sum += p[j];
    }
#pragma unroll
    for (int off = 32; off > 0; off >>= 1) sum += __shfl_xor(sum, off, 64);
    const float inv = RCPF(sum);
#pragma unroll
    for (int j = 0; j < 8; ++j) sc[w][l + (j << 6)] = p[j] * inv;
  }
  __syncthreads();

  // repack: thread t writes attnT[b][k=t][q0..q0+3] as one float4
  const float4 o = make_float4(sc[0][t], sc[1][t], sc[2][t], sc[3][t]);
  *reinterpret_cast<float4*>(attnT + ((size_t)(b * NK + t)) * NQ + q0) = o;
}

// ---------------------------------------------------------------------------
// K3: partial[ks][b][q][v] = sum_{k in split} attnT[b][k][q]*values[b][k][v]
// 128x128 C-tile, 512 threads (8 waves -> 2/SIMD), 4x8 micro-tile, BK=16,
// 4-way K-split -> 256 blocks. Splits past valid_len store zeros and exit.
// ---------------------------------------------------------------------------
__global__ __launch_bounds__(512) void pv_gemm_kernel(
    const float* __restrict__ attnT, const float* __restrict__ values,
    const int* __restrict__ valid_lens, float* __restrict__ partial) {
  const int bid = blockIdx.x;
  const int ks = bid & 3;
  const int tile = (bid >> 2) & 15;
  const int b = bid >> 6;
  const int q0 = (tile >> 2) << 7;
  const int v0 = (tile & 3) << 7;
  const int kbase = ks << 7;

  __shared__ __align__(16) float aT[16][128];
  __shared__ __align__(16) float bS[16][128];

  const int tid = threadIdx.x;
  const int tv = tid & 15, tq = tid >> 4;  // tv 0..15, tq 0..31

  float acc[4][8];
#pragma unroll
  for (int i = 0; i < 4; ++i)
#pragma unroll
    for (int j = 0; j < 8; ++j) acc[i][j] = 0.f;

  if (kbase < valid_lens[b]) {  // else: all-zero attn rows, store zeros
    const int sdk = tid >> 5, sc4 = (tid & 31) << 2;  // one float4 per tile
    for (int kt = 0; kt < 8; ++kt) {
      const int k0 = kbase + (kt << 4);
      *reinterpret_cast<float4*>(&aT[sdk][sc4]) =
          *reinterpret_cast<const float4*>(attnT + ((size_t)(b * NK + k0 + sdk)) * NQ + q0 + sc4);
      *reinterpret_cast<float4*>(&bS[sdk][sc4]) =
          *reinterpret_cast<const float4*>(values + ((size_t)(b * NK + k0 + sdk)) * DV + v0 + sc4);
      __syncthreads();
#pragma unroll
      for (int dk = 0; dk < 16; ++dk) {
        const float4 a4 = *reinterpret_cast<const float4*>(&aT[dk][tq << 2]);
        const float4 b0 = *reinterpret_cast<const float4*>(&bS[dk][tv << 2]);
        const float4 b1 = *reinterpret_cast<const float4*>(&bS[dk][64 + (tv << 2)]);
        const float av[4] = {a4.x, a4.y, a4.z, a4.w};
        const float bv[8] = {b0.x, b0.y, b0.z, b0.w, b1.x, b1.y, b1.z, b1.w};
#pragma unroll
        for (int i = 0; i < 4; ++i)
#pragma unroll
          for (int j = 0; j < 8; ++j) acc[i][j] = fmaf(av[i], bv[j], acc[i][j]);
      }
      __syncthreads();
    }
  }

  float* pbase = partial + ((size_t)(ks * NB + b)) * NQ * DV;
#pragma unroll
  for (int i = 0; i < 4; ++i) {
    float* row = pbase + ((size_t)(q0 + (tq << 2) + i)) * DV + v0;
    *reinterpret_cast<float4*>(row + (tv << 2)) =
        make_float4(acc[i][0], acc[i][1], acc[i][2], acc[i][3]);
    *reinterpret_cast<float4*>(row + 64 + (tv << 2)) =
        make_float4(acc[i][4], acc[i][5], acc[i][6], acc[i][7]);
  }
}

// ---------------------------------------------------------------------------
// K4: out = sum of the 4 K-split partials (deterministic, no atomics)
// ---------------------------------------------------------------------------
__global__ __launch_bounds__(256) void reduce4_kernel(
    const float* __restrict__ partial, float* __restrict__ out) {
  const int i = blockIdx.x * 256 + threadIdx.x;  // float4 index, 262144 total
  const float4* p = reinterpret_cast<const float4*>(partial);
  const float4 a = p[i];
  const float4 b = p[i + 262144];
  const float4 c = p[i + 524288];
  const float4 d = p[i + 786432];
  float4 r;
  r.x = a.x + b.x + c.x + d.x;
  r.y = a.y + b.y + c.y + d.y;
  r.z = a.z + b.z + c.z + d.z;
  r.w = a.w + b.w + c.w + d.w;
  reinterpret_cast<float4*>(out)[i] = r;
}

extern "C" void kernel_launch(void* const* d_in, const int* in_sizes, int n_in,
                              void* d_out, int out_size, void* d_ws, size_t ws_size,
                              hipStream_t stream) {
  (void)in_sizes; (void)n_in; (void)out_size; (void)ws_size;
  const float* queries = (const float*)d_in[0];
  const float* keys    = (const float*)d_in[1];
  const float* values  = (const float*)d_in[2];
  const float* Wq      = (const float*)d_in[3];
  const float* Wk      = (const float*)d_in[4];
  const float* Wv      = (const float*)d_in[5];
  const int*   vlens   = (const int*)d_in[6];
  float* out = (float*)d_out;
  float* ws = (float*)d_ws;

  // ws layout (floats): eq 262144 | ek 262144 | attnT 1048576 | partial 4x1048576
  float* eq    = ws;
  float* ek    = ws + 262144;
  float* attnT = ws + 524288;
  float* part  = ws + 1572864;

  proj_exp_kernel<<<1024, 256, 0, stream>>>(queries, keys, Wq, Wk, eq, ek, vlens);
  scores_softmax_kernel<<<NB * 128, 512, 0, stream>>>(eq, ek, Wv, vlens, attnT);
  pv_gemm_kernel<<<256, 512, 0, stream>>>(attnT, values, vlens, part);
  reduce4_kernel<<<1024, 256, 0, stream>>>(part, out);
}

// Round 3
// 61.180 us; speedup vs baseline: 1.9882x; 1.5840x over previous
//
#include <hip/hip_runtime.h>

#ifndef __has_builtin
#define __has_builtin(x) 0
#endif

#if __has_builtin(__builtin_amdgcn_exp2f)
#define EXP2F(x) __builtin_amdgcn_exp2f(x)
#else
#define EXP2F(x) exp2f(x)
#endif
#if __has_builtin(__builtin_amdgcn_rcpf)
#define RCPF(x) __builtin_amdgcn_rcpf(x)
#else
#define RCPF(x) (1.0f / (x))
#endif

static constexpr int NB = 4, NQ = 512, NK = 512, DD = 512, HH = 128, DV = 512;
static constexpr float MASKV = -1e6f;
static constexpr float C2LOG2E = 2.885390081777926814f;  // 2*log2(e)

// ---------------------------------------------------------------------------
// K1: tiled GEMM for both projections, stacked: rows 0..2047 = queries,
// rows 2048..4095 = keys. N=128, K=512 with 8-way K-split (chunk 64).
// projpart[ks][row][h] = sum_{k in chunk} in[row][k] * W[k][h].
// Tile 64x128, 256 thr, 4x8 micro-tile. Key tiles past valid_len skip
// entirely (partials stay untouched -> deterministic, outputs never read).
// ---------------------------------------------------------------------------
__global__ __launch_bounds__(256) void proj_gemm_kernel(
    const float* __restrict__ queries, const float* __restrict__ keys,
    const float* __restrict__ Wq, const float* __restrict__ Wk,
    const int* __restrict__ valid_lens, float* __restrict__ projpart) {
  const int mt = blockIdx.x >> 3;   // 0..63
  const int ks = blockIdx.x & 7;    // 0..7
  const int row0 = mt << 6;         // 0..4032
  const int k0 = ks << 6;
  const float* inb;
  const float* W;
  if (row0 >= 2048) {
    const int local = row0 - 2048;
    if ((local & 511) >= valid_lens[local >> 9]) return;  // never consumed
    inb = keys + (size_t)local * DD;
    W = Wk;
  } else {
    inb = queries + (size_t)row0 * DD;
    W = Wq;
  }

  __shared__ float aS[64][65];               // padded: conflict-free scalar r/w
  __shared__ __align__(16) float bS[64][128];

  const int t = threadIdx.x;
  // stage A: 64 rows x 64 k (coalesced float4 loads, scalar LDS writes)
#pragma unroll
  for (int f = 0; f < 4; ++f) {
    const int idx = t + (f << 8);
    const int r = idx >> 4, d0 = (idx & 15) << 2;
    const float4 v = *reinterpret_cast<const float4*>(inb + (size_t)r * DD + k0 + d0);
    aS[r][d0] = v.x; aS[r][d0 + 1] = v.y; aS[r][d0 + 2] = v.z; aS[r][d0 + 3] = v.w;
  }
  // stage B: 64 k x 128 h (coalesced, dense b128 writes)
#pragma unroll
  for (int f = 0; f < 8; ++f) {
    const int idx = t + (f << 8);
    const int dk = idx >> 5, c4 = (idx & 31) << 2;
    *reinterpret_cast<float4*>(&bS[dk][c4]) =
        *reinterpret_cast<const float4*>(W + (size_t)(k0 + dk) * HH + c4);
  }
  __syncthreads();

  const int tv = t & 15, tr = t >> 4;  // cols tv*4 & 64+tv*4, rows tr*4..+3
  float acc[4][8];
#pragma unroll
  for (int i = 0; i < 4; ++i)
#pragma unroll
    for (int j = 0; j < 8; ++j) acc[i][j] = 0.f;

#pragma unroll 8
  for (int dk = 0; dk < 64; ++dk) {
    const float a0 = aS[(tr << 2) + 0][dk];
    const float a1 = aS[(tr << 2) + 1][dk];
    const float a2 = aS[(tr << 2) + 2][dk];
    const float a3 = aS[(tr << 2) + 3][dk];
    const float4 b0 = *reinterpret_cast<const float4*>(&bS[dk][tv << 2]);
    const float4 b1 = *reinterpret_cast<const float4*>(&bS[dk][64 + (tv << 2)]);
    const float av[4] = {a0, a1, a2, a3};
    const float bv[8] = {b0.x, b0.y, b0.z, b0.w, b1.x, b1.y, b1.z, b1.w};
#pragma unroll
    for (int i = 0; i < 4; ++i)
#pragma unroll
      for (int j = 0; j < 8; ++j) acc[i][j] = fmaf(av[i], bv[j], acc[i][j]);
  }

  float* pb = projpart + ((size_t)ks << 19) + (size_t)row0 * HH;
#pragma unroll
  for (int i = 0; i < 4; ++i) {
    float* rowp = pb + (size_t)((tr << 2) + i) * HH;
    *reinterpret_cast<float4*>(rowp + (tv << 2)) =
        make_float4(acc[i][0], acc[i][1], acc[i][2], acc[i][3]);
    *reinterpret_cast<float4*>(rowp + 64 + (tv << 2)) =
        make_float4(acc[i][4], acc[i][5], acc[i][6], acc[i][7]);
  }
}

// ---------------------------------------------------------------------------
// K2: epk[row][h] = exp2( C * sum_{ks<8} projpart[ks][row][h] )
// ---------------------------------------------------------------------------
__global__ __launch_bounds__(256) void proj_reduce_kernel(
    const float* __restrict__ projpart, float* __restrict__ epk) {
  const int i = blockIdx.x * 256 + threadIdx.x;  // float4 idx, 131072 total
  const float4* p = reinterpret_cast<const float4*>(projpart);
  float4 s = p[i];
#pragma unroll
  for (int j = 1; j < 8; ++j) {
    const float4 v = p[i + j * 131072];
    s.x += v.x; s.y += v.y; s.z += v.z; s.w += v.w;
  }
  float4 r;
  r.x = EXP2F(s.x * C2LOG2E);
  r.y = EXP2F(s.y * C2LOG2E);
  r.z = EXP2F(s.z * C2LOG2E);
  r.w = EXP2F(s.w * C2LOG2E);
  reinterpret_cast<float4*>(epk)[i] = r;
}

// ---------------------------------------------------------------------------
// K3: scores + masked softmax. One block = (batch b, 4 q-rows).
// tanh(q+k) = 1 - 2/(eq*ek + 1): inner loop = fma + rcp + fma (1 trans).
// score = sum(w) - 2*sum(w*r). Writes attnT[b][k][q] (k-major).
// ---------------------------------------------------------------------------
__global__ __launch_bounds__(512) void scores_softmax_kernel(
    const float* __restrict__ eq, const float* __restrict__ ek,
    const float* __restrict__ Wv, const int* __restrict__ valid_lens,
    float* __restrict__ attnT) {
  const int b = blockIdx.x >> 7;
  const int q0 = (blockIdx.x & 127) << 2;
  const int t = threadIdx.x;

  __shared__ __align__(16) float qs[4][HH];
  __shared__ __align__(16) float wv[HH];
  __shared__ float sc[4][NK];

  qs[t >> 7][t & 127] = eq[((size_t)(b * NQ + q0 + (t >> 7))) * HH + (t & 127)];
  if (t < HH) wv[t] = Wv[t];
  __syncthreads();

  const int vl = valid_lens[b];
  float s[4] = {0.f, 0.f, 0.f, 0.f};
  float sw = 0.f;

  if (t < vl) {
    const float* ekrow = ek + ((size_t)(b * NK + t)) * HH;
    for (int hs = 0; hs < HH; hs += 4) {
      const float4 k4 = *reinterpret_cast<const float4*>(ekrow + hs);
      const float4 w4 = *reinterpret_cast<const float4*>(&wv[hs]);
      sw += (w4.x + w4.y) + (w4.z + w4.w);
#pragma unroll
      for (int q = 0; q < 4; ++q) {
        const float4 q4 = *reinterpret_cast<const float4*>(&qs[q][hs]);
        float d, r;
        d = fmaf(q4.x, k4.x, 1.f); r = RCPF(d); s[q] = fmaf(w4.x, r, s[q]);
        d = fmaf(q4.y, k4.y, 1.f); r = RCPF(d); s[q] = fmaf(w4.y, r, s[q]);
        d = fmaf(q4.z, k4.z, 1.f); r = RCPF(d); s[q] = fmaf(w4.z, r, s[q]);
        d = fmaf(q4.w, k4.w, 1.f); r = RCPF(d); s[q] = fmaf(w4.w, r, s[q]);
      }
    }
  }
#pragma unroll
  for (int q = 0; q < 4; ++q)
    sc[q][t] = (t < vl) ? fmaf(-2.f, s[q], sw) : MASKV;
  __syncthreads();

  // softmax: wave w (<4) handles q-row w over all 512 keys
  const int w = t >> 6, l = t & 63;
  if (w < 4) {
    float v[8];
#pragma unroll
    for (int j = 0; j < 8; ++j) v[j] = sc[w][l + (j << 6)];
    float m = v[0];
#pragma unroll
    for (int j = 1; j < 8; ++j) m = fmaxf(m, v[j]);
#pragma unroll
    for (int off = 32; off > 0; off >>= 1) m = fmaxf(m, __shfl_xor(m, off, 64));
    float p[8], sum = 0.f;
#pragma unroll
    for (int j = 0; j < 8; ++j) {
      p[j] = __expf(v[j] - m);  // masked: underflows to exactly 0
      sum += p[j];
    }
#pragma unroll
    for (int off = 32; off > 0; off >>= 1) sum += __shfl_xor(sum, off, 64);
    const float inv = RCPF(sum);
#pragma unroll
    for (int j = 0; j < 8; ++j) sc[w][l + (j << 6)] = p[j] * inv;
  }
  __syncthreads();

  const float4 o = make_float4(sc[0][t], sc[1][t], sc[2][t], sc[3][t]);
  *reinterpret_cast<float4*>(attnT + ((size_t)(b * NK + t)) * NQ + q0) = o;
}

// ---------------------------------------------------------------------------
// K4: partial[ks][b][q][v] = sum_{k in split} attnT[b][k][q]*values[b][k][v]
// 128x128 C-tile, 512 threads, 4x8 micro-tile, BK=16, 4-way K-split.
// ---------------------------------------------------------------------------
__global__ __launch_bounds__(512) void pv_gemm_kernel(
    const float* __restrict__ attnT, const float* __restrict__ values,
    const int* __restrict__ valid_lens, float* __restrict__ partial) {
  const int bid = blockIdx.x;
  const int ks = bid & 3;
  const int tile = (bid >> 2) & 15;
  const int b = bid >> 6;
  const int q0 = (tile >> 2) << 7;
  const int v0 = (tile & 3) << 7;
  const int kbase = ks << 7;

  __shared__ __align__(16) float aT[16][128];
  __shared__ __align__(16) float bS[16][128];

  const int tid = threadIdx.x;
  const int tv = tid & 15, tq = tid >> 4;

  float acc[4][8];
#pragma unroll
  for (int i = 0; i < 4; ++i)
#pragma unroll
    for (int j = 0; j < 8; ++j) acc[i][j] = 0.f;

  if (kbase < valid_lens[b]) {
    const int sdk = tid >> 5, sc4 = (tid & 31) << 2;
    for (int kt = 0; kt < 8; ++kt) {
      const int k0 = kbase + (kt << 4);
      *reinterpret_cast<float4*>(&aT[sdk][sc4]) =
          *reinterpret_cast<const float4*>(attnT + ((size_t)(b * NK + k0 + sdk)) * NQ + q0 + sc4);
      *reinterpret_cast<float4*>(&bS[sdk][sc4]) =
          *reinterpret_cast<const float4*>(values + ((size_t)(b * NK + k0 + sdk)) * DV + v0 + sc4);
      __syncthreads();
#pragma unroll
      for (int dk = 0; dk < 16; ++dk) {
        const float4 a4 = *reinterpret_cast<const float4*>(&aT[dk][tq << 2]);
        const float4 b0 = *reinterpret_cast<const float4*>(&bS[dk][tv << 2]);
        const float4 b1 = *reinterpret_cast<const float4*>(&bS[dk][64 + (tv << 2)]);
        const float av[4] = {a4.x, a4.y, a4.z, a4.w};
        const float bv[8] = {b0.x, b0.y, b0.z, b0.w, b1.x, b1.y, b1.z, b1.w};
#pragma unroll
        for (int i = 0; i < 4; ++i)
#pragma unroll
          for (int j = 0; j < 8; ++j) acc[i][j] = fmaf(av[i], bv[j], acc[i][j]);
      }
      __syncthreads();
    }
  }

  float* pbase = partial + ((size_t)(ks * NB + b)) * NQ * DV;
#pragma unroll
  for (int i = 0; i < 4; ++i) {
    float* row = pbase + ((size_t)(q0 + (tq << 2) + i)) * DV + v0;
    *reinterpret_cast<float4*>(row + (tv << 2)) =
        make_float4(acc[i][0], acc[i][1], acc[i][2], acc[i][3]);
    *reinterpret_cast<float4*>(row + 64 + (tv << 2)) =
        make_float4(acc[i][4], acc[i][5], acc[i][6], acc[i][7]);
  }
}

// ---------------------------------------------------------------------------
// K5: out = sum of the 4 K-split partials (deterministic, no atomics)
// ---------------------------------------------------------------------------
__global__ __launch_bounds__(256) void reduce4_kernel(
    const float* __restrict__ partial, float* __restrict__ out) {
  const int i = blockIdx.x * 256 + threadIdx.x;  // float4 index, 262144 total
  const float4* p = reinterpret_cast<const float4*>(partial);
  const float4 a = p[i];
  const float4 b = p[i + 262144];
  const float4 c = p[i + 524288];
  const float4 d = p[i + 786432];
  float4 r;
  r.x = a.x + b.x + c.x + d.x;
  r.y = a.y + b.y + c.y + d.y;
  r.z = a.z + b.z + c.z + d.z;
  r.w = a.w + b.w + c.w + d.w;
  reinterpret_cast<float4*>(out)[i] = r;
}

extern "C" void kernel_launch(void* const* d_in, const int* in_sizes, int n_in,
                              void* d_out, int out_size, void* d_ws, size_t ws_size,
                              hipStream_t stream) {
  (void)in_sizes; (void)n_in; (void)out_size; (void)ws_size;
  const float* queries = (const float*)d_in[0];
  const float* keys    = (const float*)d_in[1];
  const float* values  = (const float*)d_in[2];
  const float* Wq      = (const float*)d_in[3];
  const float* Wk      = (const float*)d_in[4];
  const float* Wv      = (const float*)d_in[5];
  const int*   vlens   = (const int*)d_in[6];
  float* out = (float*)d_out;
  float* ws = (float*)d_ws;

  // ws floats: epk 524288 | attnT 1048576 | pvpart 4194304 | projpart 4194304
  float* epk      = ws;                 // eq = rows 0..2047, ek = rows 2048..
  float* eq       = epk;
  float* ek       = epk + 262144;
  float* attnT    = ws + 524288;
  float* pvpart   = ws + 1572864;
  float* projpart = ws + 5767168;

  proj_gemm_kernel<<<512, 256, 0, stream>>>(queries, keys, Wq, Wk, vlens, projpart);
  proj_reduce_kernel<<<512, 256, 0, stream>>>(projpart, epk);
  scores_softmax_kernel<<<NB * 128, 512, 0, stream>>>(eq, ek, Wv, vlens, attnT);
  pv_gemm_kernel<<<256, 512, 0, stream>>>(attnT, values, vlens, pvpart);
  reduce4_kernel<<<1024, 256, 0, stream>>>(pvpart, out);
}